// Round 1
// 517.550 us; speedup vs baseline: 1.0659x; 1.0659x over previous
//
#include <hip/hip_runtime.h>
#include <math.h>

// fp32 in / fp32 out. Single kernel symbol, phase-switched.
// B=2,T=2048,D=1024,NH=16,NKV=4,HD=64,WIN=128,M=4096.
//
// ws layout (float slots; total used 11,272,192 < 12,582,912 known-min):
//   Y      @ 0          : QKV output f32 [4096][1536]  (dead after attn)
//   x_bf   @ 6,291,456  : x bf16 [4096][1024]          (dead after P0)
//   wqkv_bf@ 8,388,608  : [1536][1024] bf16            (dead after P0)
//   w1_bf  @ 9,175,040  : [4096][1024] bf16            (stable)
//   o_bf   @ 6,291,456  : attn out bf16 [4096][1024]   (overlays dead x_bf)
//   h_bf   @ 0          : FFN1 chunk bf16 [4096][2048] (overlays dead Y)
//   w2_bf  @ 4,194,304  : [1024][4096] bf16            (overlays dead Y tail,
//                                                       converted after attn)
// Phases: 5 convert(x,Wqkv,W1) | 0 QKV GEMM+RoPE | 2 attention |
//         6 convert(W2) | 3 FFN1 chunk (silu->bf16) | 4 FFN2 chunk (=/+=)
// GEMM: 128x128 tile, BK=64, 4 waves (2x2 of 64x64), mfma_f32_16x16x32_bf16,
//   global_load_lds width=16 staging (m97 structure). LDS 32768 B.
// Numerics identical to previous version: every operand was already rounded
// to bf16 at staging time; rounding is just moved to the producing store.

typedef __bf16 bf16x8 __attribute__((ext_vector_type(8)));
typedef __bf16 bf16x4 __attribute__((ext_vector_type(4)));
typedef float  f32x4  __attribute__((ext_vector_type(4)));

extern __shared__ __align__(16) char smem[];

#define GLOAD_LDS16(g, l) __builtin_amdgcn_global_load_lds(               \
    (const __attribute__((address_space(1))) void*)(g),                   \
    (__attribute__((address_space(3))) void*)(l), 16, 0, 0)

__global__ __launch_bounds__(256) void MultiAttention_60722247631706_kernel(
    const float* x, const float* Wq, const float* Wk, const float* Wv,
    const float* W1, const float* W2, float* out, float* ws,
    int phase, int chunk)
{
    float*  Y      = ws;
    __bf16* xbf    = (__bf16*)(ws + 6291456);
    __bf16* wqkvbf = (__bf16*)(ws + 8388608);
    __bf16* w1bf   = (__bf16*)(ws + 9175040);
    __bf16* obf    = (__bf16*)(ws + 6291456);
    __bf16* hbf    = (__bf16*)ws;
    __bf16* w2bf   = (__bf16*)(ws + 4194304);

    const int tid = threadIdx.x;

    if (phase == 5) {   // ---- convert x, Wq|Wk|Wv, W1 -> bf16
        const long long total4 = 9961472 / 4;
        for (long long i4 = (long long)blockIdx.x * 256 + tid; i4 < total4;
             i4 += (long long)gridDim.x * 256) {
            const long long i = i4 * 4;
            const float* src; __bf16* dst;
            if (i < 4194304)      { src = x  + i;             dst = xbf    + i; }
            else if (i < 5242880) { src = Wq + (i - 4194304); dst = wqkvbf + (i - 4194304); }
            else if (i < 5505024) { src = Wk + (i - 5242880); dst = wqkvbf + (i - 4194304); }
            else if (i < 5767168) { src = Wv + (i - 5505024); dst = wqkvbf + (i - 4194304); }
            else                  { src = W1 + (i - 5767168); dst = w1bf   + (i - 5767168); }
            const f32x4 v = *(const f32x4*)src;
            bf16x4 o;
            o[0] = (__bf16)v[0]; o[1] = (__bf16)v[1];
            o[2] = (__bf16)v[2]; o[3] = (__bf16)v[3];
            *(bf16x4*)dst = o;
        }
        return;
    }

    if (phase == 6) {   // ---- convert W2 -> bf16 (after attention; Y dead)
        const long long total4 = 4194304 / 4;
        for (long long i4 = (long long)blockIdx.x * 256 + tid; i4 < total4;
             i4 += (long long)gridDim.x * 256) {
            const long long i = i4 * 4;
            const f32x4 v = *(const f32x4*)(W2 + i);
            bf16x4 o;
            o[0] = (__bf16)v[0]; o[1] = (__bf16)v[1];
            o[2] = (__bf16)v[2]; o[3] = (__bf16)v[3];
            *(bf16x4*)(w2bf + i) = o;
        }
        return;
    }

    if (phase == 2) {   // ---- attention: block=(b,kvh,qi), wave=head
        float*  qs = (float*)smem;            // [4][64]
        float*  ps = qs + 256;                // [4][128]
        __bf16* Ks = (__bf16*)(ps + 512);     // [128][66]
        __bf16* Vs = Ks + 128 * 66;           // [128][66]

        const int qi   = blockIdx.x & 2047;
        const int kvb  = blockIdx.x >> 11;    // 0..7
        const int kvh  = kvb & 3;
        const int b    = kvb >> 2;
        const int w    = tid >> 6;
        const int lane = tid & 63;
        const int h    = kvh * 4 + w;

        const int jlo = qi > 127 ? qi - 127 : 0;
        const int cnt = qi - jlo + 1;         // 1..128

        const float* Kb = Y + (size_t)(b * 2048 + jlo) * 1536 + 1024 + kvh * 64;
        const float* Vb = Y + (size_t)(b * 2048 + jlo) * 1536 + 1280 + kvh * 64;

        // stage K/V window (cnt rows x 64) -> LDS bf16, row stride 66
        for (int i = tid; i < cnt * 16; i += 256) {
            const int r  = i >> 4;
            const int c4 = (i & 15) * 4;
            const f32x4 kv = *(const f32x4*)(Kb + (size_t)r * 1536 + c4);
            const f32x4 vv = *(const f32x4*)(Vb + (size_t)r * 1536 + c4);
            __bf16* kd = Ks + r * 66 + c4;
            __bf16* vd = Vs + r * 66 + c4;
            kd[0] = (__bf16)kv[0]; kd[1] = (__bf16)kv[1];
            kd[2] = (__bf16)kv[2]; kd[3] = (__bf16)kv[3];
            vd[0] = (__bf16)vv[0]; vd[1] = (__bf16)vv[1];
            vd[2] = (__bf16)vv[2]; vd[3] = (__bf16)vv[3];
        }
        qs[w * 64 + lane] = Y[(size_t)(b * 2048 + qi) * 1536 + h * 64 + lane];
        __syncthreads();

        float s0 = -1e30f, s1 = -1e30f;
        if (lane < cnt) {
            const __bf16* kp = Ks + lane * 66;
            float acc = 0.f;
#pragma unroll 8
            for (int d = 0; d < 64; ++d) acc += (float)kp[d] * qs[w * 64 + d];
            s0 = acc * 0.125f;
        }
        if (lane + 64 < cnt) {
            const __bf16* kp = Ks + (lane + 64) * 66;
            float acc = 0.f;
#pragma unroll 8
            for (int d = 0; d < 64; ++d) acc += (float)kp[d] * qs[w * 64 + d];
            s1 = acc * 0.125f;
        }

        float mx = fmaxf(s0, s1);
        for (int off = 32; off; off >>= 1) mx = fmaxf(mx, __shfl_xor(mx, off));
        const float p0 = (s0 > -1e29f) ? expf(s0 - mx) : 0.f;
        const float p1 = (s1 > -1e29f) ? expf(s1 - mx) : 0.f;
        float sum = p0 + p1;
        for (int off = 32; off; off >>= 1) sum += __shfl_xor(sum, off);
        ps[w * 128 + lane]      = p0;
        ps[w * 128 + 64 + lane] = p1;
        __syncthreads();

        const float rs = 1.f / sum;
        float acc = 0.f;
#pragma unroll 4
        for (int jj = 0; jj < cnt; ++jj)
            acc += ps[w * 128 + jj] * (float)Vs[jj * 66 + lane];
        obf[(size_t)(b * 2048 + qi) * 1024 + h * 64 + lane] = (__bf16)(acc * rs);
        return;
    }

    // ---- phases 0/3/4: 128x128 MFMA GEMM, C[M,N]=A[M,K]@Brow[N,K]^T
    __bf16* As = (__bf16*)smem;       // [128][64]
    __bf16* Bs = As + 128 * 64;       // [128][64]

    const __bf16* Ap; const __bf16* Bp; int lda, ldb, K, ntn;
    if (phase == 0) {
        Ap = xbf; lda = 1024; Bp = wqkvbf; ldb = 1024; K = 1024; ntn = 12;
    } else if (phase == 3) {
        Ap = obf; lda = 1024; Bp = w1bf + (size_t)chunk * 2048 * 1024;
        ldb = 1024; K = 1024; ntn = 16;
    } else {
        Ap = hbf; lda = 2048; Bp = w2bf + chunk * 2048;
        ldb = 4096; K = 2048; ntn = 8;
    }

    const int tm   = blockIdx.x / ntn;
    const int tn   = blockIdx.x % ntn;
    const int w    = tid >> 6;
    const int lane = tid & 63;
    const int wr   = w >> 1;
    const int wc   = w & 1;
    const int l16  = lane & 15;
    const int quad = lane >> 4;
    const int l8r  = lane >> 3;          // row within an 8-row group
    const int l8c  = (lane & 7) * 8;     // elem col within the group

    // per-lane global sources for the wave's 4 x 8-row staging groups
    const __bf16* ga0 = Ap + (size_t)(tm * 128 + w * 32 + l8r) * lda + l8c;
    const __bf16* gb0 = Bp + (size_t)(tn * 128 + w * 32 + l8r) * ldb + l8c;

    f32x4 zero = {0.f, 0.f, 0.f, 0.f};
    f32x4 acc[4][4];
#pragma unroll
    for (int mi = 0; mi < 4; ++mi)
#pragma unroll
        for (int ni = 0; ni < 4; ++ni) acc[mi][ni] = zero;

    for (int k0 = 0; k0 < K; k0 += 64) {
#pragma unroll
        for (int i = 0; i < 4; ++i) {
            // LDS dest is wave-uniform base; HW scatters lane*16B
            GLOAD_LDS16(ga0 + (size_t)i * 8 * lda + k0, As + (w * 32 + i * 8) * 64);
            GLOAD_LDS16(gb0 + (size_t)i * 8 * ldb + k0, Bs + (w * 32 + i * 8) * 64);
        }
        __syncthreads();
#pragma unroll
        for (int kk = 0; kk < 2; ++kk) {
            const int ko = kk * 32 + quad * 8;
            bf16x8 af[4], bfr[4];
#pragma unroll
            for (int mi = 0; mi < 4; ++mi)
                af[mi] = *(const bf16x8*)(As + (size_t)(wr * 64 + mi * 16 + l16) * 64 + ko);
#pragma unroll
            for (int ni = 0; ni < 4; ++ni)
                bfr[ni] = *(const bf16x8*)(Bs + (size_t)(wc * 64 + ni * 16 + l16) * 64 + ko);
#pragma unroll
            for (int mi = 0; mi < 4; ++mi)
#pragma unroll
                for (int ni = 0; ni < 4; ++ni)
                    acc[mi][ni] = __builtin_amdgcn_mfma_f32_16x16x32_bf16(
                        af[mi], bfr[ni], acc[mi][ni], 0, 0, 0);
        }
        __syncthreads();
    }

    // D: m = tm*128 + wr*64 + mi*16 + quad*4 + r ; n = tn*128 + wc*64 + ni*16 + l16
    const int mbase = tm * 128 + wr * 64;
    const int nbase = tn * 128 + wc * 64;   // multiple of 64 -> one head per group

    if (phase == 0) {
        // Fused RoPE: pairs (ni=0,ni=2) give d=l16 / d+32; (1,3) give 16+l16.
        const bool rot = nbase < 1280;      // Q (n<1024) and K (1024..1279)
        const float inv1 = powf(10000.f, -(float)l16 / 32.f);
        const float inv2 = powf(10000.f, -(float)(16 + l16) / 32.f);
#pragma unroll
        for (int mi = 0; mi < 4; ++mi) {
#pragma unroll
            for (int r = 0; r < 4; ++r) {
                const int m = mbase + mi * 16 + quad * 4 + r;
                const int t = m & 2047;
                float v0 = acc[mi][0][r], v1 = acc[mi][1][r];
                float v2 = acc[mi][2][r], v3 = acc[mi][3][r];
                if (rot) {
                    const float a1 = (float)t * inv1, a2 = (float)t * inv2;
                    const float c1 = cosf(a1), s1 = sinf(a1);
                    const float c2 = cosf(a2), s2 = sinf(a2);
                    const float n0 = v0 * c1 - v2 * s1;
                    const float n2 = v0 * s1 + v2 * c1;
                    const float n1 = v1 * c2 - v3 * s2;
                    const float n3 = v1 * s2 + v3 * c2;
                    v0 = n0; v1 = n1; v2 = n2; v3 = n3;
                }
                float* yp = Y + (size_t)m * 1536 + nbase + l16;
                yp[0] = v0; yp[16] = v1; yp[32] = v2; yp[48] = v3;
            }
        }
    } else if (phase == 3) {
#pragma unroll
        for (int mi = 0; mi < 4; ++mi) {
#pragma unroll
            for (int r = 0; r < 4; ++r) {
                const int m = mbase + mi * 16 + quad * 4 + r;
                __bf16* hp = hbf + (size_t)m * 2048 + nbase + l16;
#pragma unroll
                for (int ni = 0; ni < 4; ++ni) {
                    const float v = acc[mi][ni][r];
                    hp[ni * 16] = (__bf16)(v / (1.f + expf(-v)));   // silu
                }
            }
        }
    } else {
#pragma unroll
        for (int mi = 0; mi < 4; ++mi) {
#pragma unroll
            for (int r = 0; r < 4; ++r) {
                const int m = mbase + mi * 16 + quad * 4 + r;
                float* op = out + (size_t)m * 1024 + nbase + l16;
#pragma unroll
                for (int ni = 0; ni < 4; ++ni) {
                    const float v = acc[mi][ni][r];
                    if (chunk == 0) op[ni * 16] = v;
                    else            op[ni * 16] += v;
                }
            }
        }
    }
}

extern "C" void kernel_launch(void* const* d_in, const int* in_sizes, int n_in,
                              void* d_out, int out_size, void* d_ws, size_t ws_size,
                              hipStream_t stream)
{
    const float* x  = (const float*)d_in[0];
    const float* Wq = (const float*)d_in[1];
    const float* Wk = (const float*)d_in[2];
    const float* Wv = (const float*)d_in[3];
    const float* W1 = (const float*)d_in[4];
    const float* W2 = (const float*)d_in[5];
    float* out = (float*)d_out;
    float* ws  = (float*)d_ws;

    const int GEMM_LDS = 2 * 128 * 64 * 2;                       // 32768 B
    const int ATTN_LDS = 256 * 4 + 512 * 4 + 2 * 128 * 66 * 2;   // 36864 B

    // conv: x, Wq|Wk|Wv, W1 -> bf16
    MultiAttention_60722247631706_kernel<<<2048, 256, 0, stream>>>(
        x, Wq, Wk, Wv, W1, W2, out, ws, 5, 0);
    // P0: QKV GEMM + fused RoPE -> Y: (4096/128)*(1536/128) = 384 blocks
    MultiAttention_60722247631706_kernel<<<384, 256, GEMM_LDS, stream>>>(
        x, Wq, Wk, Wv, W1, W2, out, ws, 0, 0);
    // P2: attention: (b,kvh,qi) = 2*4*2048 = 16384 blocks -> o_bf
    MultiAttention_60722247631706_kernel<<<16384, 256, ATTN_LDS, stream>>>(
        x, Wq, Wk, Wv, W1, W2, out, ws, 2, 0);
    // conv: W2 -> bf16 (Y now dead)
    MultiAttention_60722247631706_kernel<<<1024, 256, 0, stream>>>(
        x, Wq, Wk, Wv, W1, W2, out, ws, 6, 0);
    // FFN chunks: FFN1 32*16 = 512 blocks; FFN2 32*8 = 256 blocks
    MultiAttention_60722247631706_kernel<<<512, 256, GEMM_LDS, stream>>>(
        x, Wq, Wk, Wv, W1, W2, out, ws, 3, 0);
    MultiAttention_60722247631706_kernel<<<256, 256, GEMM_LDS, stream>>>(
        x, Wq, Wk, Wv, W1, W2, out, ws, 4, 0);
    MultiAttention_60722247631706_kernel<<<512, 256, GEMM_LDS, stream>>>(
        x, Wq, Wk, Wv, W1, W2, out, ws, 3, 1);
    MultiAttention_60722247631706_kernel<<<256, 256, GEMM_LDS, stream>>>(
        x, Wq, Wk, Wv, W1, W2, out, ws, 4, 1);
}

// Round 2
// 337.936 us; speedup vs baseline: 1.6324x; 1.5315x over previous
//
#include <hip/hip_runtime.h>
#include <math.h>

// fp32 in / fp32 out. Three kernel symbols (conv / gemm / attn) so each
// phase gets its own VGPR budget (r1 lesson: shared symbol cost attention
// half its occupancy).
// B=2,T=2048,D=1024,NH=16,NKV=4,HD=64,WIN=128,M=4096.
//
// ws layout (float slots):
//   Y      @ 0          : QKV output f32 [4096][1536]  (dead after attn)
//   x_bf   @ 6,291,456  : x bf16 [4096][1024]          (dead after P0)
//   wqkv_bf@ 8,388,608  : [1536][1024] bf16            (dead after P0)
//   w1_bf  @ 9,175,040  : [4096][1024] bf16            (stable)
//   o_bf   @ 6,291,456  : attn out bf16 [4096][1024]   (overlays dead x_bf)
//   h_bf   @ 0          : FFN1 chunk bf16 [4096][2048] (overlays dead Y)
//   w2_bf  @ 4,194,304  : [1024][4096] bf16            (overlays dead Y tail)
//
// Attention (MFMA flash): grid 256 = (b=2, kvh=4, qt=32), 4 waves = 4 GQA
// heads of one kv head. LDS: K [192][72] bf16 + V^T [64][200] bf16 = 53248 B.
// Swapped QK^T: S^T = mfma(A=K, B=Q) -> lane holds q=l16 (row-reduce =
// shfl_xor 16/32). Online softmax over 3 key-blocks of 64. P->A-fragment
// relayout: S^T lane holds (k=km*16+quad*4+r, q=l16); PV A-frag needs
// (m=q=l16, k=quad*8+j). For target quad: km=2kk+(quad>>1), src quads
// (quad&1)*2 and +1, same l16 -> 8 shfl per (qm,kk).
// MFMA layouts (HW-verified m89/m91): A[m=lane&15][k=(lane>>4)*8+j],
//   B[n=lane&15][k=same], D: col=lane&15, row=(lane>>4)*4+reg.

typedef __bf16 bf16x8 __attribute__((ext_vector_type(8)));
typedef __bf16 bf16x4 __attribute__((ext_vector_type(4)));
typedef float  f32x4  __attribute__((ext_vector_type(4)));

extern __shared__ __align__(16) char smem[];

#define GLOAD_LDS16(g, l) __builtin_amdgcn_global_load_lds(               \
    (const __attribute__((address_space(1))) void*)(g),                   \
    (__attribute__((address_space(3))) void*)(l), 16, 0, 0)

__device__ __forceinline__ unsigned pk2(float a, float b) {
    union { __bf16 h[2]; unsigned u; } t;
    t.h[0] = (__bf16)a; t.h[1] = (__bf16)b;
    return t.u;
}

// ---------------------------------------------------------------- conv ----
__global__ __launch_bounds__(256) void MultiAttention_60722247631706_conv(
    const float* x, const float* Wq, const float* Wk, const float* Wv,
    const float* W1, const float* W2, float* ws, int phase)
{
    __bf16* xbf    = (__bf16*)(ws + 6291456);
    __bf16* wqkvbf = (__bf16*)(ws + 8388608);
    __bf16* w1bf   = (__bf16*)(ws + 9175040);
    __bf16* w2bf   = (__bf16*)(ws + 4194304);
    const int tid = threadIdx.x;

    if (phase == 5) {
        const long long total4 = 9961472 / 4;
        for (long long i4 = (long long)blockIdx.x * 256 + tid; i4 < total4;
             i4 += (long long)gridDim.x * 256) {
            const long long i = i4 * 4;
            const float* src; __bf16* dst;
            if (i < 4194304)      { src = x  + i;             dst = xbf    + i; }
            else if (i < 5242880) { src = Wq + (i - 4194304); dst = wqkvbf + (i - 4194304); }
            else if (i < 5505024) { src = Wk + (i - 5242880); dst = wqkvbf + (i - 4194304); }
            else if (i < 5767168) { src = Wv + (i - 5505024); dst = wqkvbf + (i - 4194304); }
            else                  { src = W1 + (i - 5767168); dst = w1bf   + (i - 5767168); }
            const f32x4 v = *(const f32x4*)src;
            bf16x4 o;
            o[0] = (__bf16)v[0]; o[1] = (__bf16)v[1];
            o[2] = (__bf16)v[2]; o[3] = (__bf16)v[3];
            *(bf16x4*)dst = o;
        }
    } else {
        const long long total4 = 4194304 / 4;
        for (long long i4 = (long long)blockIdx.x * 256 + tid; i4 < total4;
             i4 += (long long)gridDim.x * 256) {
            const long long i = i4 * 4;
            const f32x4 v = *(const f32x4*)(W2 + i);
            bf16x4 o;
            o[0] = (__bf16)v[0]; o[1] = (__bf16)v[1];
            o[2] = (__bf16)v[2]; o[3] = (__bf16)v[3];
            *(bf16x4*)(w2bf + i) = o;
        }
    }
}

// ---------------------------------------------------------------- attn ----
__global__ __launch_bounds__(256) void MultiAttention_60722247631706_attn(
    float* ws)
{
    const float* Y = ws;
    __bf16* obf = (__bf16*)(ws + 6291456);

    __bf16* Ks = (__bf16*)smem;          // [192][72]
    __bf16* Vt = Ks + 192 * 72;          // [64][200]  (V transposed: Vt[d][j])

    const int qt  = blockIdx.x & 31;
    const int kvh = (blockIdx.x >> 5) & 3;
    const int b   = blockIdx.x >> 7;
    const int q0  = qt * 64;
    const int wb  = q0 - 128;            // LDS row r <-> key j = wb + r

    const int tid  = threadIdx.x;
    const int w    = tid >> 6;
    const int lane = tid & 63;
    const int l16  = lane & 15;
    const int quad = lane >> 4;
    const int h    = kvh * 4 + w;

    const float* Yb = Y + (size_t)b * 2048 * 1536;

    // stage K window -> bf16 LDS [192][72]
    for (int i = tid; i < 192 * 8; i += 256) {
        const int r  = i >> 3;
        const int c8 = (i & 7) * 8;
        const int j  = wb + r;
        bf16x8 kv;
        if (j >= 0) {
            const float* kp = Yb + (size_t)j * 1536 + 1024 + kvh * 64 + c8;
            const f32x4 a = *(const f32x4*)kp;
            const f32x4 c = *(const f32x4*)(kp + 4);
            kv[0] = (__bf16)a[0]; kv[1] = (__bf16)a[1];
            kv[2] = (__bf16)a[2]; kv[3] = (__bf16)a[3];
            kv[4] = (__bf16)c[0]; kv[5] = (__bf16)c[1];
            kv[6] = (__bf16)c[2]; kv[7] = (__bf16)c[3];
        } else {
            const __bf16 z = (__bf16)0.f;
            kv[0]=z; kv[1]=z; kv[2]=z; kv[3]=z; kv[4]=z; kv[5]=z; kv[6]=z; kv[7]=z;
        }
        *(bf16x8*)(Ks + r * 72 + c8) = kv;
    }
    // stage V transposed -> Vt[d][r], stride 200 (zeros for j<0: p=0*garbage guard)
    for (int i = tid; i < 192 * 16; i += 256) {
        const int r  = i >> 4;
        const int c4 = (i & 15) * 4;
        const int j  = wb + r;
        f32x4 vv = {0.f, 0.f, 0.f, 0.f};
        if (j >= 0) vv = *(const f32x4*)(Yb + (size_t)j * 1536 + 1280 + kvh * 64 + c4);
        Vt[(c4 + 0) * 200 + r] = (__bf16)vv[0];
        Vt[(c4 + 1) * 200 + r] = (__bf16)vv[1];
        Vt[(c4 + 2) * 200 + r] = (__bf16)vv[2];
        Vt[(c4 + 3) * 200 + r] = (__bf16)vv[3];
    }

    // Q B-fragments (scale 0.125 folded in): qf[qn][kk], q=l16, d=kk*32+quad*8+j
    bf16x8 qf[4][2];
#pragma unroll
    for (int qn = 0; qn < 4; ++qn)
#pragma unroll
        for (int kk = 0; kk < 2; ++kk) {
            const float* qp = Yb + (size_t)(q0 + qn * 16 + l16) * 1536
                              + h * 64 + kk * 32 + quad * 8;
            const f32x4 a = *(const f32x4*)qp;
            const f32x4 c = *(const f32x4*)(qp + 4);
            bf16x8 t;
            t[0] = (__bf16)(a[0] * 0.125f); t[1] = (__bf16)(a[1] * 0.125f);
            t[2] = (__bf16)(a[2] * 0.125f); t[3] = (__bf16)(a[3] * 0.125f);
            t[4] = (__bf16)(c[0] * 0.125f); t[5] = (__bf16)(c[1] * 0.125f);
            t[6] = (__bf16)(c[2] * 0.125f); t[7] = (__bf16)(c[3] * 0.125f);
            qf[qn][kk] = t;
        }

    __syncthreads();

    f32x4 oacc[4][4];
#pragma unroll
    for (int qm = 0; qm < 4; ++qm)
#pragma unroll
        for (int dn = 0; dn < 4; ++dn) {
            f32x4 z = {0.f, 0.f, 0.f, 0.f};
            oacc[qm][dn] = z;
        }
    float m_run[4] = {-1e30f, -1e30f, -1e30f, -1e30f};
    float l_run[4] = {0.f, 0.f, 0.f, 0.f};

    const int kclip = -wb;               // j>=0  <=>  k_local >= kclip

    for (int kb = 0; kb < 3; ++kb) {
        // ---- S^T = K @ Q^T for this 64-key block
        f32x4 s[4][4];
#pragma unroll
        for (int km = 0; km < 4; ++km)
#pragma unroll
            for (int qn = 0; qn < 4; ++qn) {
                f32x4 z = {0.f, 0.f, 0.f, 0.f};
                s[km][qn] = z;
            }
#pragma unroll
        for (int kk = 0; kk < 2; ++kk) {
            bf16x8 kf[4];
#pragma unroll
            for (int km = 0; km < 4; ++km)
                kf[km] = *(const bf16x8*)(Ks + (kb * 64 + km * 16 + l16) * 72
                                          + kk * 32 + quad * 8);
#pragma unroll
            for (int km = 0; km < 4; ++km)
#pragma unroll
                for (int qn = 0; qn < 4; ++qn)
                    s[km][qn] = __builtin_amdgcn_mfma_f32_16x16x32_bf16(
                        kf[km], qf[qn][kk], s[km][qn], 0, 0, 0);
        }

        // ---- mask + online softmax (per q row = fixed l16, reduce over quads)
        unsigned cu[4][4][2];
        float corr[4];
#pragma unroll
        for (int qn = 0; qn < 4; ++qn) {
            float mx = -1e30f;
#pragma unroll
            for (int km = 0; km < 4; ++km)
#pragma unroll
                for (int r = 0; r < 4; ++r) {
                    const int kl  = kb * 64 + km * 16 + quad * 4 + r;
                    const int dlt = kl - (qn * 16 + l16);
                    const bool ok = (dlt >= 1) && (dlt <= 128) && (kl >= kclip);
                    const float sv = ok ? s[km][qn][r] : -1e30f;
                    s[km][qn][r] = sv;
                    mx = fmaxf(mx, sv);
                }
            mx = fmaxf(mx, __shfl_xor(mx, 16));
            mx = fmaxf(mx, __shfl_xor(mx, 32));
            const float mnew = fmaxf(fmaxf(m_run[qn], mx), -1e20f);
            corr[qn] = expf(m_run[qn] - mnew);   // first block: exp(-inf)=0
            m_run[qn] = mnew;
            float rowsum = 0.f;
#pragma unroll
            for (int km = 0; km < 4; ++km) {
#pragma unroll
                for (int r = 0; r < 4; ++r) {
                    const float p = expf(s[km][qn][r] - mnew);  // masked -> 0
                    s[km][qn][r] = p;
                    rowsum += p;
                }
                cu[qn][km][0] = pk2(s[km][qn][0], s[km][qn][1]);
                cu[qn][km][1] = pk2(s[km][qn][2], s[km][qn][3]);
            }
            rowsum += __shfl_xor(rowsum, 16);
            rowsum += __shfl_xor(rowsum, 32);
            l_run[qn] = l_run[qn] * corr[qn] + rowsum;
        }

        // ---- rescale O (row q=quad*4+r needs corr from lane l16=quad*4+r)
#pragma unroll
        for (int qm = 0; qm < 4; ++qm)
#pragma unroll
            for (int r = 0; r < 4; ++r) {
                const float f = __shfl(corr[qm], (lane & 48) | (quad * 4 + r));
                oacc[qm][0][r] *= f; oacc[qm][1][r] *= f;
                oacc[qm][2][r] *= f; oacc[qm][3][r] *= f;
            }

        // ---- PV: O += P @ V  (A-frag built by cross-quad shfl of cu packs)
#pragma unroll
        for (int kk = 0; kk < 2; ++kk) {
            bf16x8 vf[4];
#pragma unroll
            for (int dn = 0; dn < 4; ++dn)
                vf[dn] = *(const bf16x8*)(Vt + (dn * 16 + l16) * 200
                                          + kb * 64 + kk * 32 + quad * 8);
            const int srcA = ((quad & 1) * 32) + l16;
            const int hi   = quad >> 1;
#pragma unroll
            for (int qm = 0; qm < 4; ++qm) {
                const unsigned a0 = (unsigned)__shfl((int)cu[qm][2*kk  ][0], srcA);
                const unsigned a1 = (unsigned)__shfl((int)cu[qm][2*kk  ][1], srcA);
                const unsigned b0 = (unsigned)__shfl((int)cu[qm][2*kk+1][0], srcA);
                const unsigned b1 = (unsigned)__shfl((int)cu[qm][2*kk+1][1], srcA);
                const unsigned c0 = (unsigned)__shfl((int)cu[qm][2*kk  ][0], srcA + 16);
                const unsigned c1 = (unsigned)__shfl((int)cu[qm][2*kk  ][1], srcA + 16);
                const unsigned d0 = (unsigned)__shfl((int)cu[qm][2*kk+1][0], srcA + 16);
                const unsigned d1 = (unsigned)__shfl((int)cu[qm][2*kk+1][1], srcA + 16);
                union { unsigned u[4]; bf16x8 v; } af;
                af.u[0] = hi ? b0 : a0;
                af.u[1] = hi ? b1 : a1;
                af.u[2] = hi ? d0 : c0;
                af.u[3] = hi ? d1 : c1;
#pragma unroll
                for (int dn = 0; dn < 4; ++dn)
                    oacc[qm][dn] = __builtin_amdgcn_mfma_f32_16x16x32_bf16(
                        af.v, vf[dn], oacc[qm][dn], 0, 0, 0);
            }
        }
    }

    // ---- normalize + store bf16
#pragma unroll
    for (int qm = 0; qm < 4; ++qm) {
        const float rl = 1.f / l_run[qm];
#pragma unroll
        for (int r = 0; r < 4; ++r) {
            const float f = __shfl(rl, (lane & 48) | (quad * 4 + r));
            const int q = q0 + qm * 16 + quad * 4 + r;
            __bf16* op = obf + ((size_t)(b * 2048 + q)) * 1024 + h * 64 + l16;
#pragma unroll
            for (int dn = 0; dn < 4; ++dn)
                op[dn * 16] = (__bf16)(oacc[qm][dn][r] * f);
        }
    }
}

// ---------------------------------------------------------------- gemm ----
__global__ __launch_bounds__(256) void MultiAttention_60722247631706_kernel(
    float* out, float* ws, int phase, int chunk)
{
    float*  Y      = ws;
    __bf16* xbf    = (__bf16*)(ws + 6291456);
    __bf16* wqkvbf = (__bf16*)(ws + 8388608);
    __bf16* w1bf   = (__bf16*)(ws + 9175040);
    __bf16* obf    = (__bf16*)(ws + 6291456);
    __bf16* hbf    = (__bf16*)ws;
    __bf16* w2bf   = (__bf16*)(ws + 4194304);

    const int tid = threadIdx.x;

    __bf16* As = (__bf16*)smem;       // [128][64]
    __bf16* Bs = As + 128 * 64;       // [128][64]

    const __bf16* Ap; const __bf16* Bp; int lda, ldb, K, ntn;
    if (phase == 0) {
        Ap = xbf; lda = 1024; Bp = wqkvbf; ldb = 1024; K = 1024; ntn = 12;
    } else if (phase == 3) {
        Ap = obf; lda = 1024; Bp = w1bf + (size_t)chunk * 2048 * 1024;
        ldb = 1024; K = 1024; ntn = 16;
    } else {
        Ap = hbf; lda = 2048; Bp = w2bf + chunk * 2048;
        ldb = 4096; K = 2048; ntn = 8;
    }

    const int tm   = blockIdx.x / ntn;
    const int tn   = blockIdx.x % ntn;
    const int w    = tid >> 6;
    const int lane = tid & 63;
    const int wr   = w >> 1;
    const int wc   = w & 1;
    const int l16  = lane & 15;
    const int quad = lane >> 4;
    const int l8r  = lane >> 3;
    const int l8c  = (lane & 7) * 8;

    const __bf16* ga0 = Ap + (size_t)(tm * 128 + w * 32 + l8r) * lda + l8c;
    const __bf16* gb0 = Bp + (size_t)(tn * 128 + w * 32 + l8r) * ldb + l8c;

    f32x4 zero = {0.f, 0.f, 0.f, 0.f};
    f32x4 acc[4][4];
#pragma unroll
    for (int mi = 0; mi < 4; ++mi)
#pragma unroll
        for (int ni = 0; ni < 4; ++ni) acc[mi][ni] = zero;

    for (int k0 = 0; k0 < K; k0 += 64) {
#pragma unroll
        for (int i = 0; i < 4; ++i) {
            GLOAD_LDS16(ga0 + (size_t)i * 8 * lda + k0, As + (w * 32 + i * 8) * 64);
            GLOAD_LDS16(gb0 + (size_t)i * 8 * ldb + k0, Bs + (w * 32 + i * 8) * 64);
        }
        __syncthreads();
#pragma unroll
        for (int kk = 0; kk < 2; ++kk) {
            const int ko = kk * 32 + quad * 8;
            bf16x8 af[4], bfr[4];
#pragma unroll
            for (int mi = 0; mi < 4; ++mi)
                af[mi] = *(const bf16x8*)(As + (size_t)(wr * 64 + mi * 16 + l16) * 64 + ko);
#pragma unroll
            for (int ni = 0; ni < 4; ++ni)
                bfr[ni] = *(const bf16x8*)(Bs + (size_t)(wc * 64 + ni * 16 + l16) * 64 + ko);
#pragma unroll
            for (int mi = 0; mi < 4; ++mi)
#pragma unroll
                for (int ni = 0; ni < 4; ++ni)
                    acc[mi][ni] = __builtin_amdgcn_mfma_f32_16x16x32_bf16(
                        af[mi], bfr[ni], acc[mi][ni], 0, 0, 0);
        }
        __syncthreads();
    }

    const int mbase = tm * 128 + wr * 64;
    const int nbase = tn * 128 + wc * 64;

    if (phase == 0) {
        const bool rot = nbase < 1280;      // Q (n<1024) and K (1024..1279)
        const float inv1 = powf(10000.f, -(float)l16 / 32.f);
        const float inv2 = powf(10000.f, -(float)(16 + l16) / 32.f);
#pragma unroll
        for (int mi = 0; mi < 4; ++mi) {
#pragma unroll
            for (int r = 0; r < 4; ++r) {
                const int m = mbase + mi * 16 + quad * 4 + r;
                const int t = m & 2047;
                float v0 = acc[mi][0][r], v1 = acc[mi][1][r];
                float v2 = acc[mi][2][r], v3 = acc[mi][3][r];
                if (rot) {
                    const float a1 = (float)t * inv1, a2 = (float)t * inv2;
                    const float c1 = cosf(a1), s1 = sinf(a1);
                    const float c2 = cosf(a2), s2 = sinf(a2);
                    const float n0 = v0 * c1 - v2 * s1;
                    const float n2 = v0 * s1 + v2 * c1;
                    const float n1 = v1 * c2 - v3 * s2;
                    const float n3 = v1 * s2 + v3 * c2;
                    v0 = n0; v1 = n1; v2 = n2; v3 = n3;
                }
                float* yp = Y + (size_t)m * 1536 + nbase + l16;
                yp[0] = v0; yp[16] = v1; yp[32] = v2; yp[48] = v3;
            }
        }
    } else if (phase == 3) {
#pragma unroll
        for (int mi = 0; mi < 4; ++mi) {
#pragma unroll
            for (int r = 0; r < 4; ++r) {
                const int m = mbase + mi * 16 + quad * 4 + r;
                __bf16* hp = hbf + (size_t)m * 2048 + nbase + l16;
#pragma unroll
                for (int ni = 0; ni < 4; ++ni) {
                    const float v = acc[mi][ni][r];
                    hp[ni * 16] = (__bf16)(v / (1.f + expf(-v)));   // silu
                }
            }
        }
    } else {
#pragma unroll
        for (int mi = 0; mi < 4; ++mi) {
#pragma unroll
            for (int r = 0; r < 4; ++r) {
                const int m = mbase + mi * 16 + quad * 4 + r;
                float* op = out + (size_t)m * 1024 + nbase + l16;
#pragma unroll
                for (int ni = 0; ni < 4; ++ni) {
                    const float v = acc[mi][ni][r];
                    if (chunk == 0) op[ni * 16] = v;
                    else            op[ni * 16] += v;
                }
            }
        }
    }
}

extern "C" void kernel_launch(void* const* d_in, const int* in_sizes, int n_in,
                              void* d_out, int out_size, void* d_ws, size_t ws_size,
                              hipStream_t stream)
{
    const float* x  = (const float*)d_in[0];
    const float* Wq = (const float*)d_in[1];
    const float* Wk = (const float*)d_in[2];
    const float* Wv = (const float*)d_in[3];
    const float* W1 = (const float*)d_in[4];
    const float* W2 = (const float*)d_in[5];
    float* out = (float*)d_out;
    float* ws  = (float*)d_ws;

    const int GEMM_LDS = 2 * 128 * 64 * 2;                 // 32768 B
    const int ATTN_LDS = (192 * 72 + 64 * 200) * 2;        // 53248 B

    // conv: x, Wq|Wk|Wv, W1 -> bf16
    MultiAttention_60722247631706_conv<<<2048, 256, 0, stream>>>(
        x, Wq, Wk, Wv, W1, W2, ws, 5);
    // P0: QKV GEMM + fused RoPE -> Y f32 [4096][1536]
    MultiAttention_60722247631706_kernel<<<384, 256, GEMM_LDS, stream>>>(
        out, ws, 0, 0);
    // attention: 256 blocks = (b,kvh,qtile64), MFMA flash -> o_bf
    MultiAttention_60722247631706_attn<<<256, 256, ATTN_LDS, stream>>>(ws);
    // conv: W2 -> bf16 (Y now dead)
    MultiAttention_60722247631706_conv<<<1024, 256, 0, stream>>>(
        x, Wq, Wk, Wv, W1, W2, ws, 6);
    // FFN chunks
    MultiAttention_60722247631706_kernel<<<512, 256, GEMM_LDS, stream>>>(
        out, ws, 3, 0);
    MultiAttention_60722247631706_kernel<<<256, 256, GEMM_LDS, stream>>>(
        out, ws, 4, 0);
    MultiAttention_60722247631706_kernel<<<512, 256, GEMM_LDS, stream>>>(
        out, ws, 3, 1);
    MultiAttention_60722247631706_kernel<<<256, 256, GEMM_LDS, stream>>>(
        out, ws, 4, 1);
}

// Round 3
// 304.299 us; speedup vs baseline: 1.8128x; 1.1105x over previous
//
#include <hip/hip_runtime.h>
#include <math.h>

// fp32 in / fp32 out. Three kernel symbols (conv / gemm / attn).
// B=2,T=2048,D=1024,NH=16,NKV=4,HD=64,WIN=128,M=4096.
//
// ws layout (float slots; max used 12,582,912):
//   Y      @ 0           : QKV f32 [4096][1536]        (dead after attn)
//   x_bf   @ 6,291,456   : x bf16 [4096][1024]         (dead after P0)
//   wqkv_bf@ 8,388,608   : [1536][1024] bf16           (dead after P0)
//   o_bf   @ 8,388,608   : attn out bf16 [4096][1024]  (over wqkv; dead after P3)
//   w1_bf  @ 10,485,760  : [4096][1024] bf16           (dead after P3)
//   h_bf   @ 0           : FFN1 out bf16 [4096][4096]  (over dead Y+x_bf)
//   w2_bf  @ 8,388,608   : [1024][4096] bf16           (over dead o_bf, conv6)
//
// Sequence: conv5(x,Wqkv,W1) | P0 QKV GEMM+RoPE->Y | attn->o_bf |
//           conv6(W2->w2_bf, zero out) | P3 FFN1 full (1024 blk, silu->h_bf) |
//           P4 FFN2 split-K x4 (1024 blk, atomicAdd out).
//   (conv6 placed after P3 in launch order? NO - conv6 must run after P3
//    because w2_bf overlays o_bf which P3 reads. Order: P3 then conv6 then P4.)
//
// GEMM: 128x128 tile, BK=64, 4 waves, mfma_f32_16x16x32_bf16,
//   global_load_lds width=16. LDS tiles XOR-swizzled (r2: 6.29M bank-conflict
//   cycles = 2x LDS cost): physical chunk16B = logical ^ (row&7); writes are
//   pre-swizzled at the per-lane GLOBAL source (rule: gload_lds dest must be
//   linear), reads apply the same XOR.
// MFMA layouts (HW-verified m89/m91): A[m=lane&15][k=(lane>>4)*8+j],
//   B[n=lane&15][k=same], D: col=lane&15, row=(lane>>4)*4+reg.

typedef __bf16 bf16x8 __attribute__((ext_vector_type(8)));
typedef __bf16 bf16x4 __attribute__((ext_vector_type(4)));
typedef float  f32x4  __attribute__((ext_vector_type(4)));

extern __shared__ __align__(16) char smem[];

#define GLOAD_LDS16(g, l) __builtin_amdgcn_global_load_lds(               \
    (const __attribute__((address_space(1))) void*)(g),                   \
    (__attribute__((address_space(3))) void*)(l), 16, 0, 0)

__device__ __forceinline__ unsigned pk2(float a, float b) {
    union { __bf16 h[2]; unsigned u; } t;
    t.h[0] = (__bf16)a; t.h[1] = (__bf16)b;
    return t.u;
}

// ---------------------------------------------------------------- conv ----
__global__ __launch_bounds__(256) void MultiAttention_60722247631706_conv(
    const float* x, const float* Wq, const float* Wk, const float* Wv,
    const float* W1, const float* W2, float* out, float* ws, int phase)
{
    __bf16* xbf    = (__bf16*)(ws + 6291456);
    __bf16* wqkvbf = (__bf16*)(ws + 8388608);
    __bf16* w1bf   = (__bf16*)(ws + 10485760);
    __bf16* w2bf   = (__bf16*)(ws + 8388608);
    const int tid = threadIdx.x;

    if (phase == 5) {
        const long long total4 = 9961472 / 4;
        for (long long i4 = (long long)blockIdx.x * 256 + tid; i4 < total4;
             i4 += (long long)gridDim.x * 256) {
            const long long i = i4 * 4;
            const float* src; __bf16* dst;
            if (i < 4194304)      { src = x  + i;             dst = xbf    + i; }
            else if (i < 5242880) { src = Wq + (i - 4194304); dst = wqkvbf + (i - 4194304); }
            else if (i < 5505024) { src = Wk + (i - 5242880); dst = wqkvbf + (i - 4194304); }
            else if (i < 5767168) { src = Wv + (i - 5505024); dst = wqkvbf + (i - 4194304); }
            else                  { src = W1 + (i - 5767168); dst = w1bf   + (i - 5767168); }
            const f32x4 v = *(const f32x4*)src;
            bf16x4 o;
            o[0] = (__bf16)v[0]; o[1] = (__bf16)v[1];
            o[2] = (__bf16)v[2]; o[3] = (__bf16)v[3];
            *(bf16x4*)dst = o;
        }
    } else {
        // convert W2 -> w2_bf, and zero `out` for P4's atomic split-K
        const long long total4 = 4194304 / 4;
        for (long long i4 = (long long)blockIdx.x * 256 + tid; i4 < total4;
             i4 += (long long)gridDim.x * 256) {
            const long long i = i4 * 4;
            const f32x4 v = *(const f32x4*)(W2 + i);
            bf16x4 o;
            o[0] = (__bf16)v[0]; o[1] = (__bf16)v[1];
            o[2] = (__bf16)v[2]; o[3] = (__bf16)v[3];
            *(bf16x4*)(w2bf + i) = o;
        }
        const f32x4 z = {0.f, 0.f, 0.f, 0.f};
        for (long long i4 = (long long)blockIdx.x * 256 + tid; i4 < total4;
             i4 += (long long)gridDim.x * 256) {
            *(f32x4*)(out + i4 * 4) = z;
        }
    }
}

// ---------------------------------------------------------------- attn ----
__global__ __launch_bounds__(256) void MultiAttention_60722247631706_attn(
    float* ws)
{
    const float* Y = ws;
    __bf16* obf = (__bf16*)(ws + 8388608);

    __bf16* Ks = (__bf16*)smem;          // [192][72]
    __bf16* Vt = Ks + 192 * 72;          // [64][200]  (V transposed: Vt[d][j])

    const int qt  = blockIdx.x & 31;
    const int kvh = (blockIdx.x >> 5) & 3;
    const int b   = blockIdx.x >> 7;
    const int q0  = qt * 64;
    const int wb  = q0 - 128;            // LDS row r <-> key j = wb + r

    const int tid  = threadIdx.x;
    const int w    = tid >> 6;
    const int lane = tid & 63;
    const int l16  = lane & 15;
    const int quad = lane >> 4;
    const int h    = kvh * 4 + w;

    const float* Yb = Y + (size_t)b * 2048 * 1536;

    // stage K window -> bf16 LDS [192][72]
    for (int i = tid; i < 192 * 8; i += 256) {
        const int r  = i >> 3;
        const int c8 = (i & 7) * 8;
        const int j  = wb + r;
        bf16x8 kv;
        if (j >= 0) {
            const float* kp = Yb + (size_t)j * 1536 + 1024 + kvh * 64 + c8;
            const f32x4 a = *(const f32x4*)kp;
            const f32x4 c = *(const f32x4*)(kp + 4);
            kv[0] = (__bf16)a[0]; kv[1] = (__bf16)a[1];
            kv[2] = (__bf16)a[2]; kv[3] = (__bf16)a[3];
            kv[4] = (__bf16)c[0]; kv[5] = (__bf16)c[1];
            kv[6] = (__bf16)c[2]; kv[7] = (__bf16)c[3];
        } else {
            const __bf16 z = (__bf16)0.f;
            kv[0]=z; kv[1]=z; kv[2]=z; kv[3]=z; kv[4]=z; kv[5]=z; kv[6]=z; kv[7]=z;
        }
        *(bf16x8*)(Ks + r * 72 + c8) = kv;
    }
    // stage V transposed -> Vt[d][r], stride 200
    for (int i = tid; i < 192 * 16; i += 256) {
        const int r  = i >> 4;
        const int c4 = (i & 15) * 4;
        const int j  = wb + r;
        f32x4 vv = {0.f, 0.f, 0.f, 0.f};
        if (j >= 0) vv = *(const f32x4*)(Yb + (size_t)j * 1536 + 1280 + kvh * 64 + c4);
        Vt[(c4 + 0) * 200 + r] = (__bf16)vv[0];
        Vt[(c4 + 1) * 200 + r] = (__bf16)vv[1];
        Vt[(c4 + 2) * 200 + r] = (__bf16)vv[2];
        Vt[(c4 + 3) * 200 + r] = (__bf16)vv[3];
    }

    // Q B-fragments (scale folded): qf[qn][kk], q=l16, d=kk*32+quad*8+j
    bf16x8 qf[4][2];
#pragma unroll
    for (int qn = 0; qn < 4; ++qn)
#pragma unroll
        for (int kk = 0; kk < 2; ++kk) {
            const float* qp = Yb + (size_t)(q0 + qn * 16 + l16) * 1536
                              + h * 64 + kk * 32 + quad * 8;
            const f32x4 a = *(const f32x4*)qp;
            const f32x4 c = *(const f32x4*)(qp + 4);
            bf16x8 t;
            t[0] = (__bf16)(a[0] * 0.125f); t[1] = (__bf16)(a[1] * 0.125f);
            t[2] = (__bf16)(a[2] * 0.125f); t[3] = (__bf16)(a[3] * 0.125f);
            t[4] = (__bf16)(c[0] * 0.125f); t[5] = (__bf16)(c[1] * 0.125f);
            t[6] = (__bf16)(c[2] * 0.125f); t[7] = (__bf16)(c[3] * 0.125f);
            qf[qn][kk] = t;
        }

    __syncthreads();

    f32x4 oacc[4][4];
#pragma unroll
    for (int qm = 0; qm < 4; ++qm)
#pragma unroll
        for (int dn = 0; dn < 4; ++dn) {
            f32x4 z = {0.f, 0.f, 0.f, 0.f};
            oacc[qm][dn] = z;
        }
    float m_run[4] = {-1e30f, -1e30f, -1e30f, -1e30f};
    float l_run[4] = {0.f, 0.f, 0.f, 0.f};

    const int kclip = -wb;               // j>=0  <=>  k_local >= kclip

    for (int kb = 0; kb < 3; ++kb) {
        f32x4 s[4][4];
#pragma unroll
        for (int km = 0; km < 4; ++km)
#pragma unroll
            for (int qn = 0; qn < 4; ++qn) {
                f32x4 z = {0.f, 0.f, 0.f, 0.f};
                s[km][qn] = z;
            }
#pragma unroll
        for (int kk = 0; kk < 2; ++kk) {
            bf16x8 kf[4];
#pragma unroll
            for (int km = 0; km < 4; ++km)
                kf[km] = *(const bf16x8*)(Ks + (kb * 64 + km * 16 + l16) * 72
                                          + kk * 32 + quad * 8);
#pragma unroll
            for (int km = 0; km < 4; ++km)
#pragma unroll
                for (int qn = 0; qn < 4; ++qn)
                    s[km][qn] = __builtin_amdgcn_mfma_f32_16x16x32_bf16(
                        kf[km], qf[qn][kk], s[km][qn], 0, 0, 0);
        }

        unsigned cu[4][4][2];
        float corr[4];
#pragma unroll
        for (int qn = 0; qn < 4; ++qn) {
            float mx = -1e30f;
#pragma unroll
            for (int km = 0; km < 4; ++km)
#pragma unroll
                for (int r = 0; r < 4; ++r) {
                    const int kl  = kb * 64 + km * 16 + quad * 4 + r;
                    const int dlt = kl - (qn * 16 + l16);
                    const bool ok = (dlt >= 1) && (dlt <= 128) && (kl >= kclip);
                    const float sv = ok ? s[km][qn][r] : -1e30f;
                    s[km][qn][r] = sv;
                    mx = fmaxf(mx, sv);
                }
            mx = fmaxf(mx, __shfl_xor(mx, 16));
            mx = fmaxf(mx, __shfl_xor(mx, 32));
            const float mnew = fmaxf(fmaxf(m_run[qn], mx), -1e20f);
            corr[qn] = expf(m_run[qn] - mnew);
            m_run[qn] = mnew;
            float rowsum = 0.f;
#pragma unroll
            for (int km = 0; km < 4; ++km) {
#pragma unroll
                for (int r = 0; r < 4; ++r) {
                    const float p = expf(s[km][qn][r] - mnew);
                    s[km][qn][r] = p;
                    rowsum += p;
                }
                cu[qn][km][0] = pk2(s[km][qn][0], s[km][qn][1]);
                cu[qn][km][1] = pk2(s[km][qn][2], s[km][qn][3]);
            }
            rowsum += __shfl_xor(rowsum, 16);
            rowsum += __shfl_xor(rowsum, 32);
            l_run[qn] = l_run[qn] * corr[qn] + rowsum;
        }

#pragma unroll
        for (int qm = 0; qm < 4; ++qm)
#pragma unroll
            for (int r = 0; r < 4; ++r) {
                const float f = __shfl(corr[qm], (lane & 48) | (quad * 4 + r));
                oacc[qm][0][r] *= f; oacc[qm][1][r] *= f;
                oacc[qm][2][r] *= f; oacc[qm][3][r] *= f;
            }

#pragma unroll
        for (int kk = 0; kk < 2; ++kk) {
            bf16x8 vf[4];
#pragma unroll
            for (int dn = 0; dn < 4; ++dn)
                vf[dn] = *(const bf16x8*)(Vt + (dn * 16 + l16) * 200
                                          + kb * 64 + kk * 32 + quad * 8);
            const int srcA = ((quad & 1) * 32) + l16;
            const int hi   = quad >> 1;
#pragma unroll
            for (int qm = 0; qm < 4; ++qm) {
                const unsigned a0 = (unsigned)__shfl((int)cu[qm][2*kk  ][0], srcA);
                const unsigned a1 = (unsigned)__shfl((int)cu[qm][2*kk  ][1], srcA);
                const unsigned b0 = (unsigned)__shfl((int)cu[qm][2*kk+1][0], srcA);
                const unsigned b1 = (unsigned)__shfl((int)cu[qm][2*kk+1][1], srcA);
                const unsigned c0 = (unsigned)__shfl((int)cu[qm][2*kk  ][0], srcA + 16);
                const unsigned c1 = (unsigned)__shfl((int)cu[qm][2*kk  ][1], srcA + 16);
                const unsigned d0 = (unsigned)__shfl((int)cu[qm][2*kk+1][0], srcA + 16);
                const unsigned d1 = (unsigned)__shfl((int)cu[qm][2*kk+1][1], srcA + 16);
                union { unsigned u[4]; bf16x8 v; } af;
                af.u[0] = hi ? b0 : a0;
                af.u[1] = hi ? b1 : a1;
                af.u[2] = hi ? d0 : c0;
                af.u[3] = hi ? d1 : c1;
#pragma unroll
                for (int dn = 0; dn < 4; ++dn)
                    oacc[qm][dn] = __builtin_amdgcn_mfma_f32_16x16x32_bf16(
                        af.v, vf[dn], oacc[qm][dn], 0, 0, 0);
            }
        }
    }

#pragma unroll
    for (int qm = 0; qm < 4; ++qm) {
        const float rl = 1.f / l_run[qm];
#pragma unroll
        for (int r = 0; r < 4; ++r) {
            const float f = __shfl(rl, (lane & 48) | (quad * 4 + r));
            const int q = q0 + qm * 16 + quad * 4 + r;
            __bf16* op = obf + ((size_t)(b * 2048 + q)) * 1024 + h * 64 + l16;
#pragma unroll
            for (int dn = 0; dn < 4; ++dn)
                op[dn * 16] = (__bf16)(oacc[qm][dn][r] * f);
        }
    }
}

// ---------------------------------------------------------------- gemm ----
// phase 0: Y = x@Wqkv^T (+RoPE)    grid 32*12
// phase 3: H = silu(o@W1^T) full   grid 32*32
// phase 4: out += Hks@W2ks^T       grid 4*32*8 (split-K, atomicAdd)
__global__ __launch_bounds__(256) void MultiAttention_60722247631706_kernel(
    float* out, float* ws, int phase)
{
    float*  Y      = ws;
    __bf16* xbf    = (__bf16*)(ws + 6291456);
    __bf16* wqkvbf = (__bf16*)(ws + 8388608);
    __bf16* w1bf   = (__bf16*)(ws + 10485760);
    __bf16* obf    = (__bf16*)(ws + 8388608);
    __bf16* hbf    = (__bf16*)ws;
    __bf16* w2bf   = (__bf16*)(ws + 8388608);

    const int tid = threadIdx.x;

    __bf16* As = (__bf16*)smem;       // [128][64] (chunk-swizzled)
    __bf16* Bs = As + 128 * 64;       // [128][64]

    const __bf16* Ap; const __bf16* Bp; int lda, ldb, ntn, kbase;
    int bid = blockIdx.x;
    if (phase == 0) {
        Ap = xbf; lda = 1024; Bp = wqkvbf; ldb = 1024; ntn = 12; kbase = 0;
    } else if (phase == 3) {
        Ap = obf; lda = 1024; Bp = w1bf;   ldb = 1024; ntn = 32; kbase = 0;
    } else {
        const int ks = bid >> 8;  bid &= 255;
        Ap = hbf; lda = 4096; Bp = w2bf;   ldb = 4096; ntn = 8;
        kbase = ks * 1024;
    }
    const int K = 1024;   // per-slice K for all phases

    const int tm   = bid / ntn;
    const int tn   = bid % ntn;
    const int w    = tid >> 6;
    const int lane = tid & 63;
    const int wr   = w >> 1;
    const int wc   = w & 1;
    const int l16  = lane & 15;
    const int quad = lane >> 4;
    const int srow = lane >> 3;                  // 0..7
    const int sch  = ((lane & 7) ^ srow) * 8;    // pre-swizzled source chunk

    const __bf16* ga0 = Ap + (size_t)(tm * 128 + w * 32 + srow) * lda + kbase + sch;
    const __bf16* gb0 = Bp + (size_t)(tn * 128 + w * 32 + srow) * ldb + kbase + sch;

    f32x4 zero = {0.f, 0.f, 0.f, 0.f};
    f32x4 acc[4][4];
#pragma unroll
    for (int mi = 0; mi < 4; ++mi)
#pragma unroll
        for (int ni = 0; ni < 4; ++ni) acc[mi][ni] = zero;

    for (int k0 = 0; k0 < K; k0 += 64) {
#pragma unroll
        for (int i = 0; i < 4; ++i) {
            GLOAD_LDS16(ga0 + (size_t)i * 8 * lda + k0, As + (w * 32 + i * 8) * 64);
            GLOAD_LDS16(gb0 + (size_t)i * 8 * ldb + k0, Bs + (w * 32 + i * 8) * 64);
        }
        __syncthreads();
#pragma unroll
        for (int kk = 0; kk < 2; ++kk) {
            const int cs = ((kk * 4 + quad) ^ (l16 & 7)) * 8;  // swizzled read
            bf16x8 af[4], bfr[4];
#pragma unroll
            for (int mi = 0; mi < 4; ++mi)
                af[mi] = *(const bf16x8*)(As + (size_t)(wr * 64 + mi * 16 + l16) * 64 + cs);
#pragma unroll
            for (int ni = 0; ni < 4; ++ni)
                bfr[ni] = *(const bf16x8*)(Bs + (size_t)(wc * 64 + ni * 16 + l16) * 64 + cs);
#pragma unroll
            for (int mi = 0; mi < 4; ++mi)
#pragma unroll
                for (int ni = 0; ni < 4; ++ni)
                    acc[mi][ni] = __builtin_amdgcn_mfma_f32_16x16x32_bf16(
                        af[mi], bfr[ni], acc[mi][ni], 0, 0, 0);
        }
        __syncthreads();
    }

    const int mbase = tm * 128 + wr * 64;
    const int nbase = tn * 128 + wc * 64;

    if (phase == 0) {
        const bool rot = nbase < 1280;      // Q (n<1024) and K (1024..1279)
        const float inv1 = powf(10000.f, -(float)l16 / 32.f);
        const float inv2 = powf(10000.f, -(float)(16 + l16) / 32.f);
#pragma unroll
        for (int mi = 0; mi < 4; ++mi) {
#pragma unroll
            for (int r = 0; r < 4; ++r) {
                const int m = mbase + mi * 16 + quad * 4 + r;
                const int t = m & 2047;
                float v0 = acc[mi][0][r], v1 = acc[mi][1][r];
                float v2 = acc[mi][2][r], v3 = acc[mi][3][r];
                if (rot) {
                    const float a1 = (float)t * inv1, a2 = (float)t * inv2;
                    const float c1 = cosf(a1), s1 = sinf(a1);
                    const float c2 = cosf(a2), s2 = sinf(a2);
                    const float n0 = v0 * c1 - v2 * s1;
                    const float n2 = v0 * s1 + v2 * c1;
                    const float n1 = v1 * c2 - v3 * s2;
                    const float n3 = v1 * s2 + v3 * c2;
                    v0 = n0; v1 = n1; v2 = n2; v3 = n3;
                }
                float* yp = Y + (size_t)m * 1536 + nbase + l16;
                yp[0] = v0; yp[16] = v1; yp[32] = v2; yp[48] = v3;
            }
        }
    } else if (phase == 3) {
#pragma unroll
        for (int mi = 0; mi < 4; ++mi) {
#pragma unroll
            for (int r = 0; r < 4; ++r) {
                const int m = mbase + mi * 16 + quad * 4 + r;
                __bf16* hp = hbf + (size_t)m * 4096 + nbase + l16;
#pragma unroll
                for (int ni = 0; ni < 4; ++ni) {
                    const float v = acc[mi][ni][r];
                    hp[ni * 16] = (__bf16)(v / (1.f + expf(-v)));   // silu
                }
            }
        }
    } else {
#pragma unroll
        for (int mi = 0; mi < 4; ++mi) {
#pragma unroll
            for (int r = 0; r < 4; ++r) {
                const int m = mbase + mi * 16 + quad * 4 + r;
                float* op = out + (size_t)m * 1024 + nbase + l16;
#pragma unroll
                for (int ni = 0; ni < 4; ++ni)
                    atomicAdd(op + ni * 16, acc[mi][ni][r]);
            }
        }
    }
}

extern "C" void kernel_launch(void* const* d_in, const int* in_sizes, int n_in,
                              void* d_out, int out_size, void* d_ws, size_t ws_size,
                              hipStream_t stream)
{
    const float* x  = (const float*)d_in[0];
    const float* Wq = (const float*)d_in[1];
    const float* Wk = (const float*)d_in[2];
    const float* Wv = (const float*)d_in[3];
    const float* W1 = (const float*)d_in[4];
    const float* W2 = (const float*)d_in[5];
    float* out = (float*)d_out;
    float* ws  = (float*)d_ws;

    const int GEMM_LDS = 2 * 128 * 64 * 2;                 // 32768 B
    const int ATTN_LDS = (192 * 72 + 64 * 200) * 2;        // 53248 B

    // conv: x, Wq|Wk|Wv, W1 -> bf16
    MultiAttention_60722247631706_conv<<<2048, 256, 0, stream>>>(
        x, Wq, Wk, Wv, W1, W2, out, ws, 5);
    // P0: QKV GEMM + fused RoPE -> Y f32 [4096][1536]
    MultiAttention_60722247631706_kernel<<<384, 256, GEMM_LDS, stream>>>(
        out, ws, 0);
    // attention: 256 blocks = (b,kvh,qtile64), MFMA flash -> o_bf
    MultiAttention_60722247631706_attn<<<256, 256, ATTN_LDS, stream>>>(ws);
    // P3: FFN1 full -> h_bf (o_bf consumed here; w2_bf overlays it next)
    MultiAttention_60722247631706_kernel<<<1024, 256, GEMM_LDS, stream>>>(
        out, ws, 3);
    // conv: W2 -> bf16 (over dead o_bf) + zero `out` for atomic split-K
    MultiAttention_60722247631706_conv<<<1024, 256, 0, stream>>>(
        x, Wq, Wk, Wv, W1, W2, out, ws, 6);
    // P4: FFN2 split-K x4, atomicAdd into out
    MultiAttention_60722247631706_kernel<<<1024, 256, GEMM_LDS, stream>>>(
        out, ws, 4);
}